// Round 1
// baseline (1964.740 us; speedup 1.0000x reference)
//
#include <hip/hip_runtime.h>

#define HEADS   16
#define FEAT    32
#define D       192      // FEAT*6 flattened (feat, z, comp)
#define DPAD    196      // padded LDS row (+4 floats -> bank spread)
#define NUP     1024
#define NT      32       // q rows per block
#define MT      32       // k rows per tile
#define NTILES  (NUP/MT)
#define THREADS 256

__global__ __launch_bounds__(THREADS, 2)
void attn_fused(const float* __restrict__ x,
                const float* __restrict__ Muu, const float* __restrict__ Mdd,
                const float* __restrict__ Mud, const float* __restrict__ Mdu,
                const float* __restrict__ Auu, const float* __restrict__ Add,
                const float* __restrict__ Aud, const float* __restrict__ Adu,
                float* __restrict__ out)
{
    const int nt  = blockIdx.x;   // q tile
    const int h   = blockIdx.y;   // head
    const int t   = blockIdx.z;   // 0:uu 1:ud 2:dd 3:du
    const int tid = threadIdx.x;

    const float* qb = (t <= 1) ? x : x + (size_t)NUP*D;               // q side: u,u,d,d
    const float* kb = (t == 0 || t == 3) ? x : x + (size_t)NUP*D;     // k/v side: u,d,d,u
    const float* Mp = (t==0)?Muu:(t==1)?Mud:(t==2)?Mdd:Mdu;
    const float* Ap = (t==0)?Auu:(t==1)?Aud:(t==2)?Add:Adu;
    const float* Mh = Mp + (size_t)h*FEAT*D;   // [f][g*6+z*2+c]
    const float* Ah = Ap + (size_t)h*FEAT*D;   // [g][f*6+z*2+a]
    float* ob = out + ((t>=2) ? (size_t)NUP*D : 0);

    __shared__ float sK[MT*DPAD];      // K tile (also stages M, then A)
    __shared__ float sQM[NT*DPAD];     // QM rows (later Vtilde)
    __shared__ float sS[NT*(MT+1)];    // score tile / p tile
    __shared__ float sTmp[NT*8];
    __shared__ float sR[NT];
    __shared__ float sMaxRun[NT];
    __shared__ float sSumRun[NT];

    if (tid < NT) { sMaxRun[tid] = -3.0e38f; sSumRun[tid] = 0.0f; }

    // ---- stage M[h] flat (6144 floats) into sK ----
    for (int i = tid; i < FEAT*D/4; i += THREADS)
        reinterpret_cast<float4*>(sK)[i] = reinterpret_cast<const float4*>(Mh)[i];
    __syncthreads();

    // ---- phase 1: QM[n][g,z,b] = sum_f complexmul(q[n,f,z], M[f,g,z]) ----
    #pragma unroll
    for (int kk = 0; kk < 4; ++kk) {
        int p = tid + kk*THREADS;        // 0..1023 -> (n,g)
        int n = p >> 5, g = p & 31;
        const float* qrow = qb + (size_t)(nt*NT + n)*D;
        float acc[6] = {0,0,0,0,0,0};
        for (int f = 0; f < FEAT; ++f) {
            const float* qf = qrow + f*6;
            const float* mf = sK + f*D + g*6;
            #pragma unroll
            for (int z = 0; z < 3; ++z) {
                float q0 = qf[2*z], q1 = qf[2*z+1];
                float m0 = mf[2*z], m1 = mf[2*z+1];
                acc[2*z]   += q0*m0 - q1*m1;   // Re(q*M)
                acc[2*z+1] += q1*m0 + q0*m1;   // Im(q*M)
            }
        }
        #pragma unroll
        for (int j = 0; j < 6; ++j) sQM[n*DPAD + g*6 + j] = acc[j];
    }

    // PV register accumulators: thread owns 4 rows x 6 cols
    const int gn = tid >> 5;          // 0..7 -> rows gn*4..gn*4+3
    const int cg = tid & 31;          // col group
    const int cbase = cg*6;
    float vacc[4][6];
    #pragma unroll
    for (int a = 0; a < 4; ++a)
        #pragma unroll
        for (int b = 0; b < 6; ++b) vacc[a][b] = 0.0f;

    const int txm = tid & 15, tyn = tid >> 4;   // score 2x2 tile coords

    for (int mt = 0; mt < NTILES; ++mt) {
        __syncthreads();   // (a) prev PV done with sK/sS; QM ready on first iter
        // ---- stage K tile (32 rows x 192, padded rows) ----
        for (int i = tid; i < MT*(D/4); i += THREADS) {
            int row = i / (D/4), j = i - row*(D/4);
            float4 v = reinterpret_cast<const float4*>(kb + (size_t)(mt*MT + row)*D)[j];
            *reinterpret_cast<float4*>(&sK[row*DPAD + j*4]) = v;
        }
        __syncthreads();   // (b)

        // ---- scores: 2x2 per thread, n in {tyn,tyn+16}, m in {txm,txm+16} ----
        float a00=0,a01=0,a10=0,a11=0;
        {
            const float* q0p = &sQM[tyn*DPAD];
            const float* q1p = &sQM[(tyn+16)*DPAD];
            const float* k0p = &sK[txm*DPAD];
            const float* k1p = &sK[(txm+16)*DPAD];
            for (int k = 0; k < D; k += 4) {
                float4 qa = *reinterpret_cast<const float4*>(q0p+k);
                float4 qc = *reinterpret_cast<const float4*>(q1p+k);
                float4 ka = *reinterpret_cast<const float4*>(k0p+k);
                float4 kc = *reinterpret_cast<const float4*>(k1p+k);
                a00 += qa.x*ka.x + qa.y*ka.y + qa.z*ka.z + qa.w*ka.w;
                a01 += qa.x*kc.x + qa.y*kc.y + qa.z*kc.z + qa.w*kc.w;
                a10 += qc.x*ka.x + qc.y*ka.y + qc.z*ka.z + qc.w*ka.w;
                a11 += qc.x*kc.x + qc.y*kc.y + qc.z*kc.z + qc.w*kc.w;
            }
        }
        sS[tyn*(MT+1) + txm]          = a00;
        sS[tyn*(MT+1) + txm+16]       = a01;
        sS[(tyn+16)*(MT+1) + txm]     = a10;
        sS[(tyn+16)*(MT+1) + txm+16]  = a11;
        __syncthreads();   // (c)

        // ---- online softmax ----
        const int srow = tid >> 3, sj = tid & 7;
        {
            const float* r = &sS[srow*(MT+1)];
            float mx = fmaxf(fmaxf(r[sj], r[sj+8]), fmaxf(r[sj+16], r[sj+24]));
            sTmp[srow*8 + sj] = mx;
        }
        __syncthreads();   // (d)
        if (tid < NT) {
            float mx = sTmp[tid*8];
            #pragma unroll
            for (int j = 1; j < 8; ++j) mx = fmaxf(mx, sTmp[tid*8+j]);
            float om = sMaxRun[tid];
            float nm = fmaxf(om, mx);
            sR[tid] = __expf(om - nm);
            sMaxRun[tid] = nm;
        }
        __syncthreads();   // (e)
        {
            float nm = sMaxRun[srow];
            float* r = &sS[srow*(MT+1)];
            float p0 = __expf(r[sj]    - nm);
            float p1 = __expf(r[sj+8]  - nm);
            float p2 = __expf(r[sj+16] - nm);
            float p3 = __expf(r[sj+24] - nm);
            r[sj] = p0; r[sj+8] = p1; r[sj+16] = p2; r[sj+24] = p3;
            sTmp[srow*8+sj] = p0+p1+p2+p3;
        }
        __syncthreads();   // (f)
        if (tid < NT) {
            float s = 0.0f;
            #pragma unroll
            for (int j = 0; j < 8; ++j) s += sTmp[tid*8+j];
            sSumRun[tid] = sSumRun[tid]*sR[tid] + s;
        }

        // ---- PV accumulate (reads sS pre-(f), sR pre-(e), sK pre-(b)) ----
        {
            float r0 = sR[gn*4+0], r1 = sR[gn*4+1], r2 = sR[gn*4+2], r3 = sR[gn*4+3];
            #pragma unroll
            for (int b = 0; b < 6; ++b) { vacc[0][b]*=r0; vacc[1][b]*=r1; vacc[2][b]*=r2; vacc[3][b]*=r3; }
            for (int m = 0; m < MT; ++m) {
                float p0 = sS[(gn*4+0)*(MT+1)+m];
                float p1 = sS[(gn*4+1)*(MT+1)+m];
                float p2 = sS[(gn*4+2)*(MT+1)+m];
                float p3 = sS[(gn*4+3)*(MT+1)+m];
                const float* kr = &sK[m*DPAD + cbase];
                #pragma unroll
                for (int b = 0; b < 6; ++b) {
                    float kv = kr[b];
                    vacc[0][b] += p0*kv;
                    vacc[1][b] += p1*kv;
                    vacc[2][b] += p2*kv;
                    vacc[3][b] += p3*kv;
                }
            }
        }
    }

    __syncthreads();   // (g) PV done; sSumRun final
    // ---- write normalized Vtilde into sQM ----
    {
        float i0 = 1.0f/sSumRun[gn*4+0], i1 = 1.0f/sSumRun[gn*4+1];
        float i2 = 1.0f/sSumRun[gn*4+2], i3 = 1.0f/sSumRun[gn*4+3];
        #pragma unroll
        for (int b = 0; b < 6; ++b) {
            sQM[(gn*4+0)*DPAD + cbase + b] = vacc[0][b]*i0;
            sQM[(gn*4+1)*DPAD + cbase + b] = vacc[1][b]*i1;
            sQM[(gn*4+2)*DPAD + cbase + b] = vacc[2][b]*i2;
            sQM[(gn*4+3)*DPAD + cbase + b] = vacc[3][b]*i3;
        }
    }
    // ---- stage A[h] into sK ----
    for (int i = tid; i < FEAT*D/4; i += THREADS)
        reinterpret_cast<float4*>(sK)[i] = reinterpret_cast<const float4*>(Ah)[i];
    __syncthreads();   // (h)

    // ---- combine: out[n,g,z] += sum_f A[g,f,z] (*) Vt[n,f,z], complex ----
    #pragma unroll
    for (int kk = 0; kk < 4; ++kk) {
        int p = tid + kk*THREADS;
        int n = p >> 5, g = p & 31;
        float acc[6] = {0,0,0,0,0,0};
        const float* vb = &sQM[n*DPAD];
        const float* ab = &sK[g*D];
        for (int f = 0; f < FEAT; ++f) {
            const float* vf = vb + f*6;
            const float* af = ab + f*6;
            #pragma unroll
            for (int z = 0; z < 3; ++z) {
                float V0 = vf[2*z], V1 = vf[2*z+1];
                float A0 = af[2*z], A1 = af[2*z+1];
                acc[2*z]   += A0*V0 - A1*V1;   // ksi c=0
                acc[2*z+1] += A0*V1 + A1*V0;   // ksi c=1
            }
        }
        float* op = ob + (size_t)(nt*NT + n)*D + g*6;
        #pragma unroll
        for (int j = 0; j < 6; ++j) atomicAdd(op + j, acc[j]);
    }
}

extern "C" void kernel_launch(void* const* d_in, const int* in_sizes, int n_in,
                              void* d_out, int out_size, void* d_ws, size_t ws_size,
                              hipStream_t stream) {
    const float* x   = (const float*)d_in[0];
    const float* Muu = (const float*)d_in[1];
    const float* Mdd = (const float*)d_in[2];
    const float* Mud = (const float*)d_in[3];
    const float* Mdu = (const float*)d_in[4];
    const float* Auu = (const float*)d_in[5];
    const float* Add = (const float*)d_in[6];
    const float* Aud = (const float*)d_in[7];
    const float* Adu = (const float*)d_in[8];
    float* outp = (float*)d_out;

    hipMemsetAsync(d_out, 0, (size_t)out_size * sizeof(float), stream);
    dim3 grid(NTILES, HEADS, 4);
    attn_fused<<<grid, THREADS, 0, stream>>>(x, Muu, Mdd, Mud, Mdu,
                                             Auu, Add, Aud, Adu, outp);
}

// Round 2
// 277.111 us; speedup vs baseline: 7.0901x; 7.0901x over previous
//
#include <hip/hip_runtime.h>
#include <hip/hip_bf16.h>

typedef unsigned short u16;
typedef unsigned int   u32;
typedef short  s16x8  __attribute__((ext_vector_type(8)));
typedef float  f32x16 __attribute__((ext_vector_type(16)));

#define HEADS 16
#define D     192
#define NUP   1024

// ---- workspace layout (bytes) ----
#define QM_BYTES (4ull*16*1024*192*2)          // 25165824 (bf16)
#define QMH_OFF  0ull
#define QML_OFF  (QM_BYTES)
#define XB       (2048ull*192*2)               // 786432
#define XH_OFF   (2ull*QM_BYTES)
#define XL_OFF   (XH_OFF + XB)
#define XT_OFF   (XL_OFF + XB)
#define WT_BYTES (64ull*192*192*2)             // 4718592
#define WT_OFF   (XT_OFF + XB)
#define Y_BYTES  (4ull*16*1024*192*4)          // 50331648 (f32)
#define Y_OFF    (WT_OFF + WT_BYTES)
#define WS_NEED  (Y_OFF + Y_BYTES)             // 107741184

__device__ __forceinline__ u16 f2bf(float v) {
    __hip_bfloat16 b = __float2bfloat16(v);
    return __builtin_bit_cast(u16, b);
}

// =====================================================================
// Prep 1: QM[t][h][n][192] hi/lo bf16.  QM[n,g,z,0]=sum_f q0*M0-q1*M1,
//         QM[n,g,z,1]=sum_f q1*M0+q0*M1   (verified in round-1 fp32 path)
// =====================================================================
__global__ __launch_bounds__(256)
void prep_qm(const float* __restrict__ x,
             const float* __restrict__ Muu, const float* __restrict__ Mdd,
             const float* __restrict__ Mud, const float* __restrict__ Mdu,
             u16* __restrict__ qmh, u16* __restrict__ qml)
{
    const int nt = blockIdx.x, h = blockIdx.y, t = blockIdx.z;
    const int tid = threadIdx.x;
    const float* Mp = (t==0)?Muu:(t==1)?Mud:(t==2)?Mdd:Mdu;
    const float* Mh = Mp + (size_t)h*32*D;                 // [f][g*6+z*2+c]
    const float* qb = (t<=1) ? x : x + (size_t)NUP*D;

    __shared__ float sM[32*D];
    for (int i = tid; i < 32*D/4; i += 256)
        reinterpret_cast<float4*>(sM)[i] = reinterpret_cast<const float4*>(Mh)[i];
    __syncthreads();

    const int n  = nt*64 + (tid >> 2);
    const int gq = tid & 3;                                 // g in [gq*8, gq*8+8)
    const float* qrow = qb + (size_t)n*D;

    float acc[8][6];
    #pragma unroll
    for (int g = 0; g < 8; ++g)
        #pragma unroll
        for (int j = 0; j < 6; ++j) acc[g][j] = 0.0f;

    for (int f = 0; f < 32; ++f) {
        float2 q0 = *reinterpret_cast<const float2*>(qrow + f*6 + 0);
        float2 q1 = *reinterpret_cast<const float2*>(qrow + f*6 + 2);
        float2 q2 = *reinterpret_cast<const float2*>(qrow + f*6 + 4);
        #pragma unroll
        for (int g = 0; g < 8; ++g) {
            const float* mf = sM + f*D + (gq*8+g)*6;
            float2 m0 = *reinterpret_cast<const float2*>(mf + 0);
            float2 m1 = *reinterpret_cast<const float2*>(mf + 2);
            float2 m2 = *reinterpret_cast<const float2*>(mf + 4);
            acc[g][0] += q0.x*m0.x - q0.y*m0.y;  acc[g][1] += q0.y*m0.x + q0.x*m0.y;
            acc[g][2] += q1.x*m1.x - q1.y*m1.y;  acc[g][3] += q1.y*m1.x + q1.x*m1.y;
            acc[g][4] += q2.x*m2.x - q2.y*m2.y;  acc[g][5] += q2.y*m2.x + q2.x*m2.y;
        }
    }
    size_t base = ((size_t)(t*16+h)*1024 + n)*D + gq*48;
    #pragma unroll
    for (int g = 0; g < 8; ++g)
        #pragma unroll
        for (int j = 0; j < 6; ++j) {
            float v = acc[g][j];
            u16 hi = f2bf(v);
            float hf = __bfloat162float(__builtin_bit_cast(__hip_bfloat16, hi));
            qmh[base + g*6 + j] = hi;
            qml[base + g*6 + j] = f2bf(v - hf);
        }
}

// =====================================================================
// Prep 2: x -> xh,xl (row-major [2048][192]) and xT ([64 tiles][192][32], hi)
// =====================================================================
__global__ __launch_bounds__(512)
void prep_x(const float* __restrict__ x, u16* __restrict__ xh,
            u16* __restrict__ xl, u16* __restrict__ xT)
{
    int i = blockIdx.x*512 + threadIdx.x;      // < 2048*192
    float v = x[i];
    int n = i / D, d = i - n*D;
    u16 hi = f2bf(v);
    float hf = __bfloat162float(__builtin_bit_cast(__hip_bfloat16, hi));
    xh[i] = hi;
    xl[i] = f2bf(v - hf);
    xT[(size_t)(n >> 5)*6144 + d*32 + (n & 31)] = hi;
}

// =====================================================================
// Prep 3: WT[t*16+h][dout][din] bf16; dout=(g,z,c), din=(f,z',b), z'==z:
//   c=0: b0->A0, b1->-A1 ;  c=1: b0->A1, b1->A0
// =====================================================================
__global__ __launch_bounds__(512)
void prep_w(const float* __restrict__ Auu, const float* __restrict__ Add,
            const float* __restrict__ Aud, const float* __restrict__ Adu,
            u16* __restrict__ wt)
{
    int idx = blockIdx.x*512 + threadIdx.x;    // < 64*192*192
    int th = idx / 36864, r = idx - th*36864;
    int dout = r / 192, din = r - dout*192;
    int t = th >> 4, h = th & 15;
    const float* Ap = (t==0)?Auu:(t==1)?Aud:(t==2)?Add:Adu;
    int g = dout / 6, zc = dout - g*6, z = zc >> 1, c = zc & 1;
    int f = din / 6,  zb = din - f*6,  z2 = zb >> 1, b = zb & 1;
    float val = 0.0f;
    if (z2 == z) {
        const float* a = Ap + (((size_t)h*32 + g)*32 + f)*6 + z*2;
        float A0 = a[0], A1 = a[1];
        val = (c == 0) ? (b == 0 ? A0 : -A1) : (b == 0 ? A1 : A0);
    }
    wt[idx] = f2bf(val);
}

// =====================================================================
// helper: assemble B-fragment (32x32x16, K=16) from 4 packed-pair u32s
// held in D-frag order (m = (r&3)+8*(r>>2)+4*(lane>>5)) via half-swap
// =====================================================================
__device__ __forceinline__ s16x8 make_bfrag(u32 q0, u32 q1, u32 q2, u32 q3, bool hi) {
    u32 s0 = (u32)__shfl_xor((int)q0, 32);
    u32 s1 = (u32)__shfl_xor((int)q1, 32);
    u32 s2 = (u32)__shfl_xor((int)q2, 32);
    u32 s3 = (u32)__shfl_xor((int)q3, 32);
    uint4 w;
    w.x = hi ? s2 : q0;  w.y = hi ? s3 : q1;
    w.z = hi ? q2 : s0;  w.w = hi ? q3 : s1;
    return __builtin_bit_cast(s16x8, w);
}

// =====================================================================
// Main fused kernel: per (t,h,256-row q-tile), 8 waves x 32 q-rows.
// Flash loop over 32 k-tiles; epilogue multiplies by WT and writes
// per-(t,h) partial Y to ws.
// =====================================================================
__global__ __launch_bounds__(512, 2)
void attn_mfma(const u16* __restrict__ qmh_g, const u16* __restrict__ qml_g,
               const u16* __restrict__ xh_g,  const u16* __restrict__ xl_g,
               const u16* __restrict__ xT_g,  const u16* __restrict__ wt_g,
               float* __restrict__ y_g)
{
    const int nt = blockIdx.x, h = blockIdx.y, t = blockIdx.z;
    const int tid  = threadIdx.x;
    const int lane = tid & 63;
    const int l31  = lane & 31;
    const int g32  = lane >> 5;
    const int wave = tid >> 6;
    const int th   = t*16 + h;
    const int n0   = nt*256 + wave*32;
    const int koff = (t == 1 || t == 2) ? NUP : 0;   // k/v side rows
    const int mtb  = koff >> 5;

    __shared__ u16 sXh[32*200];
    __shared__ u16 sXl[32*200];
    __shared__ u16 sXT[192*40];

    // --- QM fragments (B operand), held in registers ---
    s16x8 qh[12], ql[12];
    {
        const u16* bh = qmh_g + ((size_t)th*1024 + n0 + l31)*D;
        const u16* bl = qml_g + ((size_t)th*1024 + n0 + l31)*D;
        #pragma unroll
        for (int ks = 0; ks < 12; ++ks) {
            qh[ks] = *reinterpret_cast<const s16x8*>(bh + ks*16 + g32*8);
            ql[ks] = *reinterpret_cast<const s16x8*>(bl + ks*16 + g32*8);
        }
    }

    f32x16 vt[6];
    #pragma unroll
    for (int ob = 0; ob < 6; ++ob)
        #pragma unroll
        for (int i = 0; i < 16; ++i) vt[ob][i] = 0.0f;

    float run_m = -3.0e38f, run_l = 0.0f;

    for (int mt = 0; mt < 32; ++mt) {
        const int krow0 = koff + mt*32;
        // A) global loads -> regs (before barrier: overlaps prev compute)
        uint4 ld[5];
        #pragma unroll
        for (int i = 0; i < 5; ++i) {
            int c = tid + i*512;
            if (c < 2304) {
                const u16* gp;
                if (c < 768) {
                    int rr = c/24, cc = c - rr*24;
                    gp = xh_g + (size_t)(krow0 + rr)*D + cc*8;
                } else if (c < 1536) {
                    int c2 = c - 768, rr = c2/24, cc = c2 - rr*24;
                    gp = xl_g + (size_t)(krow0 + rr)*D + cc*8;
                } else {
                    int c3 = c - 1536, dd = c3 >> 2, qq = c3 & 3;
                    gp = xT_g + (size_t)(mtb + mt)*6144 + dd*32 + qq*8;
                }
                ld[i] = *reinterpret_cast<const uint4*>(gp);
            }
        }
        __syncthreads();                        // prev compute done with LDS
        // B) write LDS (padded strides)
        #pragma unroll
        for (int i = 0; i < 5; ++i) {
            int c = tid + i*512;
            if (c < 2304) {
                u16* lp;
                if (c < 768) {
                    int rr = c/24, cc = c - rr*24;  lp = sXh + rr*200 + cc*8;
                } else if (c < 1536) {
                    int c2 = c - 768, rr = c2/24, cc = c2 - rr*24; lp = sXl + rr*200 + cc*8;
                } else {
                    int c3 = c - 1536, dd = c3 >> 2, qq = c3 & 3;  lp = sXT + dd*40 + qq*8;
                }
                *reinterpret_cast<uint4*>(lp) = ld[i];
            }
        }
        __syncthreads();

        // C) scores: St[m32][n32] = Xk * QM^T, 3-term split
        f32x16 s;
        #pragma unroll
        for (int i = 0; i < 16; ++i) s[i] = 0.0f;
        #pragma unroll
        for (int ks = 0; ks < 12; ++ks) {
            s16x8 ah = *reinterpret_cast<const s16x8*>(sXh + l31*200 + ks*16 + g32*8);
            s16x8 al = *reinterpret_cast<const s16x8*>(sXl + l31*200 + ks*16 + g32*8);
            s = __builtin_amdgcn_mfma_f32_32x32x16_bf16(ah, qh[ks], s, 0, 0, 0);
            s = __builtin_amdgcn_mfma_f32_32x32x16_bf16(ah, ql[ks], s, 0, 0, 0);
            s = __builtin_amdgcn_mfma_f32_32x32x16_bf16(al, qh[ks], s, 0, 0, 0);
        }

        // D) online softmax (col n = l31; lane holds 16 of 32 m values)
        float tmax = s[0];
        #pragma unroll
        for (int i = 1; i < 16; ++i) tmax = fmaxf(tmax, s[i]);
        tmax = fmaxf(tmax, __shfl_xor(tmax, 32));
        float nm = fmaxf(run_m, tmax);
        float rs = __expf(run_m - nm);
        run_m = nm;

        float p[16];
        float psum = 0.0f;
        #pragma unroll
        for (int i = 0; i < 16; ++i) { p[i] = __expf(s[i] - nm); psum += p[i]; }
        psum += __shfl_xor(psum, 32);
        run_l = run_l*rs + psum;

        #pragma unroll
        for (int ob = 0; ob < 6; ++ob)
            #pragma unroll
            for (int i = 0; i < 16; ++i) vt[ob][i] *= rs;

        // E) P -> bf16 B-fragments (in-register, half-swap)
        u32 q[8];
        #pragma unroll
        for (int j = 0; j < 8; ++j)
            q[j] = (u32)f2bf(p[2*j]) | ((u32)f2bf(p[2*j+1]) << 16);
        s16x8 pf0 = make_bfrag(q[0], q[1], q[2], q[3], g32);
        s16x8 pf1 = make_bfrag(q[4], q[5], q[6], q[7], g32);

        // F) PV: Vt^T[d][n] += X^T * P
        #pragma unroll
        for (int ob = 0; ob < 6; ++ob) {
            s16x8 a0 = *reinterpret_cast<const s16x8*>(sXT + (ob*32 + l31)*40 + g32*8);
            s16x8 a1 = *reinterpret_cast<const s16x8*>(sXT + (ob*32 + l31)*40 + 16 + g32*8);
            vt[ob] = __builtin_amdgcn_mfma_f32_32x32x16_bf16(a0, pf0, vt[ob], 0, 0, 0);
            vt[ob] = __builtin_amdgcn_mfma_f32_32x32x16_bf16(a1, pf1, vt[ob], 0, 0, 0);
        }
    }

    // --- normalize ---
    float inv = 1.0f / run_l;
    #pragma unroll
    for (int ob = 0; ob < 6; ++ob)
        #pragma unroll
        for (int i = 0; i < 16; ++i) vt[ob][i] *= inv;

    // --- combine: Y^T[dout][n] = sum_din WT[dout][din] * Vt^T[din][n] ---
    const u16* wbase = wt_g + (size_t)th*36864;
    f32x16 y[6];
    #pragma unroll
    for (int ob = 0; ob < 6; ++ob)
        #pragma unroll
        for (int i = 0; i < 16; ++i) y[ob][i] = 0.0f;

    #pragma unroll
    for (int ob = 0; ob < 6; ++ob) {
        u32 qq[8];
        #pragma unroll
        for (int j = 0; j < 8; ++j)
            qq[j] = (u32)f2bf(vt[ob][2*j]) | ((u32)f2bf(vt[ob][2*j+1]) << 16);
        #pragma unroll
        for (int half = 0; half < 2; ++half) {
            int ks = ob*2 + half;
            s16x8 b = half ? make_bfrag(qq[4], qq[5], qq[6], qq[7], g32)
                           : make_bfrag(qq[0], qq[1], qq[2], qq[3], g32);
            #pragma unroll
            for (int ob2 = 0; ob2 < 6; ++ob2) {
                s16x8 a = *reinterpret_cast<const s16x8*>(
                    wbase + (size_t)(ob2*32 + l31)*192 + ks*16 + g32*8);
                y[ob2] = __builtin_amdgcn_mfma_f32_32x32x16_bf16(a, b, y[ob2], 0, 0, 0);
            }
        }
    }

    // --- write partial Y[t][h][n][dout] (f32) ---
    float* yrow = y_g + ((size_t)th*1024 + n0 + l31)*D;
    #pragma unroll
    for (int ob = 0; ob < 6; ++ob)
        #pragma unroll
        for (int rq = 0; rq < 4; ++rq) {
            float4 v = { y[ob][rq*4+0], y[ob][rq*4+1], y[ob][rq*4+2], y[ob][rq*4+3] };
            *reinterpret_cast<float4*>(yrow + ob*32 + rq*8 + g32*4) = v;
        }
}

// =====================================================================
// Reduce: out[p*1024+n][d] = sum_{t in pair, h} y[t][h][n][d]
// =====================================================================
__global__ __launch_bounds__(512)
void reduce_y(const float* __restrict__ y_g, float* __restrict__ out)
{
    int gi = blockIdx.x*512 + threadIdx.x;     // < 2048*192/4
    int n = gi / 48, c = gi - n*48;
    int p = n >> 10, nn = n & 1023;
    const float4* yv = reinterpret_cast<const float4*>(y_g);
    float4 acc = {0, 0, 0, 0};
    #pragma unroll
    for (int k = 0; k < 32; ++k) {
        int t = p*2 + (k >> 4), hh = k & 15;
        float4 v = yv[((size_t)(t*16+hh)*1024 + nn)*48 + c];
        acc.x += v.x; acc.y += v.y; acc.z += v.z; acc.w += v.w;
    }
    reinterpret_cast<float4*>(out)[gi] = acc;
}

// =====================================================================
// Fallback (round-1 fp32 kernel, passes at ~1965us) if ws too small
// =====================================================================
__global__ __launch_bounds__(256, 2)
void attn_fused_fb(const float* __restrict__ x,
                const float* __restrict__ Muu, const float* __restrict__ Mdd,
                const float* __restrict__ Mud, const float* __restrict__ Mdu,
                const float* __restrict__ Auu, const float* __restrict__ Add,
                const float* __restrict__ Aud, const float* __restrict__ Adu,
                float* __restrict__ out)
{
    const int nt  = blockIdx.x;
    const int h   = blockIdx.y;
    const int t   = blockIdx.z;
    const int tid = threadIdx.x;
    const float* qb = (t <= 1) ? x : x + (size_t)NUP*D;
    const float* kb = (t == 0 || t == 3) ? x : x + (size_t)NUP*D;
    const float* Mp = (t==0)?Muu:(t==1)?Mud:(t==2)?Mdd:Mdu;
    const float* Ap = (t==0)?Auu:(t==1)?Aud:(t==2)?Add:Adu;
    const float* Mh = Mp + (size_t)h*32*D;
    const float* Ah = Ap + (size_t)h*32*D;
    float* ob = out + ((t>=2) ? (size_t)NUP*D : 0);

    __shared__ float sK[32*196];
    __shared__ float sQM[32*196];
    __shared__ float sS[32*33];
    __shared__ float sTmp[32*8];
    __shared__ float sR[32];
    __shared__ float sMaxRun[32];
    __shared__ float sSumRun[32];

    if (tid < 32) { sMaxRun[tid] = -3.0e38f; sSumRun[tid] = 0.0f; }
    for (int i = tid; i < 32*D/4; i += 256)
        reinterpret_cast<float4*>(sK)[i] = reinterpret_cast<const float4*>(Mh)[i];
    __syncthreads();

    #pragma unroll
    for (int kk = 0; kk < 4; ++kk) {
        int p = tid + kk*256;
        int n = p >> 5, g = p & 31;
        const float* qrow = qb + (size_t)(nt*32 + n)*D;
        float acc[6] = {0,0,0,0,0,0};
        for (int f = 0; f < 32; ++f) {
            const float* qf = qrow + f*6;
            const float* mf = sK + f*D + g*6;
            #pragma unroll
            for (int z = 0; z < 3; ++z) {
                float q0 = qf[2*z], q1 = qf[2*z+1];
                float m0 = mf[2*z], m1 = mf[2*z+1];
                acc[2*z]   += q0*m0 - q1*m1;
                acc[2*z+1] += q1*m0 + q0*m1;
            }
        }
        #pragma unroll
        for (int j = 0; j < 6; ++j) sQM[n*196 + g*6 + j] = acc[j];
    }

    const int gn = tid >> 5;
    const int cg = tid & 31;
    const int cbase = cg*6;
    float vacc[4][6];
    #pragma unroll
    for (int a = 0; a < 4; ++a)
        #pragma unroll
        for (int b = 0; b < 6; ++b) vacc[a][b] = 0.0f;

    const int txm = tid & 15, tyn = tid >> 4;

    for (int mt = 0; mt < 32; ++mt) {
        __syncthreads();
        for (int i = tid; i < 32*(D/4); i += 256) {
            int row = i / (D/4), j = i - row*(D/4);
            float4 v = reinterpret_cast<const float4*>(kb + (size_t)(mt*32 + row)*D)[j];
            *reinterpret_cast<float4*>(&sK[row*196 + j*4]) = v;
        }
        __syncthreads();

        float a00=0,a01=0,a10=0,a11=0;
        {
            const float* q0p = &sQM[tyn*196];
            const float* q1p = &sQM[(tyn+16)*196];
            const float* k0p = &sK[txm*196];
            const float* k1p = &sK[(txm+16)*196];
            for (int k = 0; k < D; k += 4) {
                float4 qa = *reinterpret_cast<const float4*>(q0p+k);
                float4 qc = *reinterpret_cast<const float4*>(q1p+k);
                float4 ka = *reinterpret_cast<const float4*>(k0p+k);
                float4 kc = *reinterpret_cast<const float4*>(k1p+k);
                a00 += qa.x*ka.x + qa.y*ka.y + qa.z*ka.z + qa.w*ka.w;
                a01 += qa.x*kc.x + qa.y*kc.y + qa.z*kc.z + qa.w*kc.w;
                a10 += qc.x*ka.x + qc.y*ka.y + qc.z*ka.z + qc.w*ka.w;
                a11 += qc.x*kc.x + qc.y*kc.y + qc.z*kc.z + qc.w*kc.w;
            }
        }
        sS[tyn*33 + txm]          = a00;
        sS[tyn*33 + txm+16]       = a01;
        sS[(tyn+16)*33 + txm]     = a10;
        sS[(tyn+16)*33 + txm+16]  = a11;
        __syncthreads();

        const int srow = tid >> 3, sj = tid & 7;
        {
            const float* r = &sS[srow*33];
            float mx = fmaxf(fmaxf(r[sj], r[sj+8]), fmaxf(r[sj+16], r[sj+24]));
            sTmp[srow*8 + sj] = mx;
        }
        __syncthreads();
        if (tid < 32) {
            float mx = sTmp[tid*8];
            #pragma unroll
            for (int j = 1; j < 8; ++j) mx = fmaxf(mx, sTmp[tid*8+j]);
            float om = sMaxRun[tid];
            float nm = fmaxf(om, mx);
            sR[tid] = __expf(om - nm);
            sMaxRun[tid] = nm;
        }
        __syncthreads();
        {
            float nm = sMaxRun[srow];
            float* r = &sS[srow*33];
            float p0 = __expf(r[sj]    - nm);
            float p1 = __expf(r[sj+8]  - nm);
            float p2 = __expf(r[sj+16] - nm);
            float p3 = __expf(r[sj+24] - nm);
            r[sj] = p0; r[sj+8] = p1; r[sj+16] = p2; r[sj+24] = p3;
            sTmp[srow*8+sj] = p0+p1+p2+p3;
        }
        __syncthreads();
        if (tid < 32) {
            float s = 0.0f;
            #pragma unroll
            for (int j = 0; j < 8; ++j) s += sTmp[tid*8+j];
            sSumRun[tid] = sSumRun[tid]*sR[tid] + s;
        }
        {
            float r0 = sR[gn*4+0], r1 = sR[gn*4+1], r2 = sR[gn*4+2], r3 = sR[gn*4+3];
            #pragma unroll
            for (int b = 0; b < 6; ++b) { vacc[0][b]*=r0; vacc[1][b]*=r1; vacc[2][b]*=r2; vacc[3][b]*=r3; }
            for (int m = 0; m < 32; ++m) {
                float p0 = sS[(gn*4+0)*33+m];
                float p1 = sS[(gn*4+1)*33+m];
                float p2 = sS[(gn*4+2)*33+m];
                float p3 = sS[(gn*4+3)*33+m];
                const float* kr = &sK[m*196 + cbase];
                #pragma unroll
                for (int b = 0; b < 6; ++b) {
                    float kv = kr[b];
                    vacc[0][b] += p0*kv;
                    vacc[1][b] += p1*kv;
                    vacc[2][b] += p2*kv;
                    vacc[3][b] += p3*kv;
                }
            }
        }
    }

    __syncthreads();
    {
        float i0 = 1.0f/sSumRun[gn*4+0], i1 = 1.0f/sSumRun[gn*4+1];
        float i2 = 1.0f/sSumRun[gn*4+2], i3 = 1.0f/sSumRun[gn*4+3];
        #pragma unroll
        for (int b = 0; b < 6; ++b) {
            sQM[(gn*4+0)*196 + cbase + b] = vacc[0][b]*i0;
            sQM[(gn*4+1)*196 + cbase + b] = vacc[1][b]*i1;
            sQM[(gn*4+2)*196 + cbase + b] = vacc[2][b]*i2;
            sQM[(gn*4+3)*196 + cbase + b] = vacc[3][b]*i3;
        }
    }
    for (int i = tid; i < 32*D/4; i += 256)
        reinterpret_cast<float4*>(sK)[i] = reinterpret_cast<const float4*>(Ah)[i];
    __syncthreads();

    #pragma unroll
    for (int kk = 0; kk < 4; ++kk) {
        int p = tid + kk*256;
        int n = p >> 5, g = p & 31;
        float acc[6] = {0,0,0,0,0,0};
        const float* vb = &sQM[n*196];
        const float* ab = &sK[g*D];
        for (int f = 0; f < 32; ++f) {
            const float* vf = vb + f*6;
            const float* af = ab + f*6;
            #pragma unroll
            for (int z = 0; z < 3; ++z) {
                float V0 = vf[2*z], V1 = vf[2*z+1];
                float A0 = af[2*z], A1 = af[2*z+1];
                acc[2*z]   += A0*V0 - A1*V1;
                acc[2*z+1] += A0*V1 + A1*V0;
            }
        }
        float* op = ob + (size_t)(nt*32 + n)*D + g*6;
        #pragma unroll
        for (int j = 0; j < 6; ++j) atomicAdd(op + j, acc[j]);
    }
}

extern "C" void kernel_launch(void* const* d_in, const int* in_sizes, int n_in,
                              void* d_out, int out_size, void* d_ws, size_t ws_size,
                              hipStream_t stream) {
    const float* x   = (const float*)d_in[0];
    const float* Muu = (const float*)d_in[1];
    const float* Mdd = (const float*)d_in[2];
    const float* Mud = (const float*)d_in[3];
    const float* Mdu = (const float*)d_in[4];
    const float* Auu = (const float*)d_in[5];
    const float* Add = (const float*)d_in[6];
    const float* Aud = (const float*)d_in[7];
    const float* Adu = (const float*)d_in[8];
    float* outp = (float*)d_out;

    if (ws_size >= WS_NEED) {
        char* ws = (char*)d_ws;
        u16*   qmh = (u16*)(ws + QMH_OFF);
        u16*   qml = (u16*)(ws + QML_OFF);
        u16*   xh  = (u16*)(ws + XH_OFF);
        u16*   xl  = (u16*)(ws + XL_OFF);
        u16*   xT  = (u16*)(ws + XT_OFF);
        u16*   wt  = (u16*)(ws + WT_OFF);
        float* y   = (float*)(ws + Y_OFF);

        prep_qm<<<dim3(16, 16, 4), 256, 0, stream>>>(x, Muu, Mdd, Mud, Mdu, qmh, qml);
        prep_x<<<768, 512, 0, stream>>>(x, xh, xl, xT);
        prep_w<<<4608, 512, 0, stream>>>(Auu, Add, Aud, Adu, wt);
        attn_mfma<<<dim3(4, 16, 4), 512, 0, stream>>>(qmh, qml, xh, xl, xT, wt, y);
        reduce_y<<<192, 512, 0, stream>>>(y, outp);
    } else {
        hipMemsetAsync(d_out, 0, (size_t)out_size * sizeof(float), stream);
        attn_fused_fb<<<dim3(32, 16, 4), 256, 0, stream>>>(x, Muu, Mdd, Mud, Mdu,
                                                           Auu, Add, Aud, Adu, outp);
    }
}